// Round 14
// baseline (239.467 us; speedup 1.0000x reference)
//
#include <hip/hip_runtime.h>

#define T_DIM 2048
#define B_DIM 8192
#define PH    256   // phases
#define SPH   8     // steps per phase

using f32x2 = __attribute__((ext_vector_type(2))) float;

// DPP cross-lane helpers (pure VALU)
__device__ __forceinline__ float dpp_qxor1(float v) {
  int i = __float_as_int(v);
  return __int_as_float(__builtin_amdgcn_update_dpp(i, i, 0xB1, 0xF, 0xF, false)); // [1,0,3,2]
}
__device__ __forceinline__ float dpp_qxor2(float v) {
  int i = __float_as_int(v);
  return __int_as_float(__builtin_amdgcn_update_dpp(i, i, 0x4E, 0xF, 0xF, false)); // [2,3,0,1]
}
__device__ __forceinline__ float dpp_qxor3(float v) {
  int i = __float_as_int(v);
  return __int_as_float(__builtin_amdgcn_update_dpp(i, i, 0x1B, 0xF, 0xF, false)); // [3,2,1,0]
}
__device__ __forceinline__ float dpp_hmirror(float v) { // lane l <- lane l^7
  int i = __float_as_int(v);
  return __int_as_float(__builtin_amdgcn_update_dpp(i, i, 0x141, 0xF, 0xF, false));
}

__global__ __launch_bounds__(768) void lstm_ch_kernel(
    const float* __restrict__ x,
    const float* __restrict__ w_ih, const float* __restrict__ w_hh,
    const float* __restrict__ b_ih, const float* __restrict__ b_hh,
    const float* __restrict__ w_lin, const float* __restrict__ b_lin,
    float* __restrict__ out)
{
  // xa: [slot][pair][k][lane] -> lane-contiguous ds ops
  __shared__ f32x2 xaBuf[2][4][SPH][64];
  // hn: [slot][pair][lane][9] (odd stride)
  __shared__ float hnBuf[2][4][64][9];

  const int tid  = threadIdx.x;
  const int wid  = tid >> 6;       // 0..11
  const int lane = tid & 63;
  const int pair = wid & 3;

  const float L2E = 1.4426950408889634f;
  const float cm2 = -2.0f * L2E;

  const int l = lane & 7;
  const int half1 = (l >> 2) & 1;            // 0: rows {i,g}; 1: rows {f,o}
  const int e = (l & 3) ^ (half1 ? 3 : 0);   // mirror partner owns same element
  const int grp = lane >> 3;
  const int rA = half1 * 4 + e;              // i | f row
  const int rB = 8 + half1 * 4 + e;          // g | o row
  const float sclA = -L2E;
  const float sclB = half1 ? -L2E : -2.0f * L2E;

  if (wid < 4) {
    // ---------------- recurrence waves (wid 0..3): 257 barriers ----------------
    __builtin_amdgcn_s_setprio(1);
    float whhA[4], whhB[4];
    #pragma unroll
    for (int k = 0; k < 4; ++k) {
      const int j = e ^ k;
      whhA[k] = sclA * w_hh[rA * 4 + j];
      whhB[k] = sclB * w_hh[rB * 4 + j];
    }
    // Z (sent across mirror / kept):
    //   half0: Z = cm2 * i * tanh(g) = cm2*(1-EB) * r   where r = 1/(dA*dB)
    //   half1: Z = f = 1/dA = r * dB
    //   -> Z = nm * rsel : half0: nm = fma(-cm2, EB, cm2), rsel = r
    //          half1: nm = dB,                rsel = r  ... unify: Z = nm * r
    const float nmA = half1 ? 0.0f : -cm2;   // nm = fma(nmA, EB, nmB) | dB for half1
    const float nmB = half1 ? 0.0f :  cm2;   // (half1 patched below: nm = dB)
    float ct = 0.0f, h0 = 0.0f, h1v = 0.0f, h2v = 0.0f, h3v = 0.0f;

    __syncthreads();  // wait for proj to fill xaBuf[0]

    for (int p = 0; p < PH; ++p) {
      const int d = p & 1;
      f32x2 xa2[SPH];
      #pragma unroll
      for (int k = 0; k < SPH; ++k) xa2[k] = xaBuf[d][pair][k][lane];  // ds_read_b64

      #pragma unroll
      for (int k = 0; k < SPH; ++k) {
        // balanced-tree gate accumulation (depth 3)
        float uA = fmaf(whhA[1], h1v, fmaf(whhA[0], h0, xa2[k][0]));
        const float vA = fmaf(whhA[3], h3v, whhA[2] * h2v);
        uA += vA;
        float uB = fmaf(whhB[1], h1v, fmaf(whhB[0], h0, xa2[k][1]));
        const float vB = fmaf(whhB[3], h3v, whhB[2] * h2v);
        uB += vB;

        const float EA = __builtin_amdgcn_exp2f(uA);
        const float EB = __builtin_amdgcn_exp2f(uB);
        const float dA = 1.0f + EA;
        const float dB = 1.0f + EB;
        // nm computed in parallel with the rcp (off the critical path)
        const float nm = half1 ? dB : fmaf(nmA, EB, nmB);
        const float r  = __builtin_amdgcn_rcpf(dA * dB);
        const float Z  = nm * r;                    // half0: cm2*i*tg ; half1: f
        const float yO = dA * r;                    // half1: sigma(o) (half0: unused)

        // exchange: half0 sends cm2*(i*tanh g), half1 sends f
        const float W = dpp_hmirror(Z);
        const float F = half1 ? Z : W;
        const float P = half1 ? W : Z;
        ct = fmaf(F, ct, P);                        // ct is cm2-scaled c

        // hn = sigma(o) * tanh(c);  tanh(c) = 2*r2 - 1  (ct pre-scaled)
        const float zc = __builtin_amdgcn_exp2f(ct);
        const float Ox = dpp_hmirror(yO);           // ship o to half0 (parallel)
        const float ov = half1 ? yO : Ox;
        const float ov2 = ov + ov;                  // ready before r2
        const float r2 = __builtin_amdgcn_rcpf(1.0f + zc);
        const float hn = fmaf(ov2, r2, -ov);        // ov*(2*r2-1), one fma after r2
        h0  = hn;
        h1v = dpp_qxor1(hn);
        h2v = dpp_qxor2(hn);
        h3v = dpp_qxor3(hn);
        hnBuf[d][pair][lane][k] = hn;
      }
      __syncthreads();
    }
  } else if (wid < 8) {
    // ---------------- proj/load waves (wid 4..7): 257 barriers ----------------
    const int b = blockIdx.x * 32 + pair * 8 + grp;
    float wihA[4], wihB[4];
    #pragma unroll
    for (int k = 0; k < 4; ++k) {
      const int j = e ^ k;
      wihA[k] = sclA * w_ih[rA * 4 + j];
      wihB[k] = sclB * w_ih[rB * 4 + j];
    }
    const float biasA = sclA * (b_ih[rA] + b_hh[rA]);
    const float biasB = sclB * (b_ih[rB] + b_hh[rB]);

    const int XS = B_DIM * 4;
    const int xoff = b * 4 + e;

    float xc[SPH], xn[SPH];

    auto load8 = [&](float (&dst)[SPH], int ph) {
      const int base = xoff + ((ph & (PH - 1)) * SPH) * XS;  // wrap: harmless
      #pragma unroll
      for (int k = 0; k < SPH; ++k) dst[k] = x[base + k * XS];
    };
    auto projWrite = [&](const float (&xr)[SPH], int dd) {
      #pragma unroll
      for (int k = 0; k < SPH; ++k) {
        const float xe = xr[k];
        const float x1 = dpp_qxor1(xe);
        const float x2 = dpp_qxor2(xe);
        const float x3 = dpp_qxor3(xe);
        f32x2 acc;
        float a = fmaf(wihA[0], xe, biasA);
        a = fmaf(wihA[1], x1, a);
        a = fmaf(wihA[2], x2, a);
        a = fmaf(wihA[3], x3, a);
        float bb = fmaf(wihB[0], xe, biasB);
        bb = fmaf(wihB[1], x1, bb);
        bb = fmaf(wihB[2], x2, bb);
        bb = fmaf(wihB[3], x3, bb);
        acc[0] = a;
        acc[1] = bb;
        xaBuf[dd][pair][k][lane] = acc;            // ds_write_b64
      }
    };

    // prologue: xa for phase 0 -> buf0; start loading x for phase 1
    load8(xc, 0);
    projWrite(xc, 0);
    load8(xn, 1);
    __syncthreads();

    for (int pp = 0; pp < PH; pp += 2) {
      projWrite(xn, 1);           // xa(pp+1) -> buf1
      load8(xc, pp + 2);
      __syncthreads();
      projWrite(xc, 0);           // xa(pp+2) -> buf0
      load8(xn, pp + 3);
      __syncthreads();
    }
  } else {
    // ---------------- head/store waves (wid 8..11): 257 barriers ----------------
    const int og = lane & 7, oj = lane >> 3;
    const int ob = blockIdx.x * 32 + pair * 8 + og;
    float wl[4];
    #pragma unroll
    for (int j = 0; j < 4; ++j) wl[j] = -L2E * w_lin[j];
    const float blin = -L2E * b_lin[0];

    __syncthreads();  // initial barrier (matches other roles)

    for (int p = 0; p < PH; ++p) {
      __syncthreads();  // barrier ending phase p -> hnBuf[p&1] complete
      const int dh = p & 1;
      const float v0 = hnBuf[dh][pair][og * 8 + 0][oj];
      const float v1 = hnBuf[dh][pair][og * 8 + 1][oj];
      const float v2 = hnBuf[dh][pair][og * 8 + 2][oj];
      const float v3 = hnBuf[dh][pair][og * 8 + 3][oj];
      float m = fmaf(wl[0], v0, blin);
      m = fmaf(wl[1], v1, m);
      m = fmaf(wl[2], v2, m);
      m = fmaf(wl[3], v3, m);
      const float o = __builtin_amdgcn_rcpf(1.0f + __builtin_amdgcn_exp2f(m));
      out[(size_t)(p * SPH + oj) * B_DIM + ob] = o;
    }
  }
}

extern "C" void kernel_launch(void* const* d_in, const int* in_sizes, int n_in,
                              void* d_out, int out_size, void* d_ws, size_t ws_size,
                              hipStream_t stream) {
  const float* x     = (const float*)d_in[0];
  const float* w_ih  = (const float*)d_in[1];
  const float* w_hh  = (const float*)d_in[2];
  const float* b_ih  = (const float*)d_in[3];
  const float* b_hh  = (const float*)d_in[4];
  const float* w_lin = (const float*)d_in[5];
  const float* b_lin = (const float*)d_in[6];
  float* out = (float*)d_out;

  // R7/R13 champion structure: 256 blocks x 768 threads (4 rec + 4 proj +
  // 4 head), 32 batch elems/block, 1 block/CU, one role per SIMD.
  // + critical-chain shortening: fused Z (nm*r), fused hn (ov2*r2-ov).
  dim3 block(768);
  dim3 grid(B_DIM / 32);
  hipLaunchKernelGGL(lstm_ch_kernel, grid, block, 0, stream,
                     x, w_ih, w_hh, b_ih, b_hh, w_lin, b_lin, out);
}

// Round 15
// 236.642 us; speedup vs baseline: 1.0119x; 1.0119x over previous
//
#include <hip/hip_runtime.h>

#define T_DIM 2048
#define B_DIM 8192
#define PH    256   // phases
#define SPH   8     // steps per phase

// DPP cross-lane helpers (pure VALU)
__device__ __forceinline__ float dpp_qxor1(float v) {
  int i = __float_as_int(v);
  return __int_as_float(__builtin_amdgcn_update_dpp(i, i, 0xB1, 0xF, 0xF, false)); // [1,0,3,2]
}
__device__ __forceinline__ float dpp_qxor2(float v) {
  int i = __float_as_int(v);
  return __int_as_float(__builtin_amdgcn_update_dpp(i, i, 0x4E, 0xF, 0xF, false)); // [2,3,0,1]
}
__device__ __forceinline__ float dpp_qxor3(float v) {
  int i = __float_as_int(v);
  return __int_as_float(__builtin_amdgcn_update_dpp(i, i, 0x1B, 0xF, 0xF, false)); // [3,2,1,0]
}

__global__ __launch_bounds__(384) void lstm_l4_kernel(
    const float* __restrict__ x,
    const float* __restrict__ w_ih, const float* __restrict__ w_hh,
    const float* __restrict__ b_ih, const float* __restrict__ b_hh,
    const float* __restrict__ w_lin, const float* __restrict__ b_lin,
    float* __restrict__ out)
{
  // xa: per lane (elem g, unit j) the four gate pre-activations (i,f,g,o)
  __shared__ float4 xaBuf[2][2][SPH][64];   // [slot][rw][k][lane]
  __shared__ float  hnBuf[2][2][64][9];     // [slot][rw][lane(4g+j)][k]

  const int tid  = threadIdx.x;
  const int wid  = tid >> 6;       // 0..5: 0,1 rec | 2,3 proj | 4,5 head
  const int lane = tid & 63;
  const int rw   = wid & 1;        // rec-wave index within block

  const float L2E = 1.4426950408889634f;
  const float cm2 = -2.0f * L2E;

  const int g = lane >> 2;         // element within wave (0..15)
  const int j = lane & 3;          // hidden unit owned by this lane

  if (wid < 2) {
    // ---------------- recurrence waves: all 4 gates of unit j in-lane ----------------
    __builtin_amdgcn_s_setprio(1);
    float wi[4], wf[4], wg[4], wo[4];   // permuted: index m pairs with h_{j^m}
    #pragma unroll
    for (int m = 0; m < 4; ++m) {
      const int jm = j ^ m;
      wi[m] = -L2E * w_hh[(0  + j) * 4 + jm];
      wf[m] = -L2E * w_hh[(4  + j) * 4 + jm];
      wg[m] = cm2  * w_hh[(8  + j) * 4 + jm];   // tanh pre-scale (-2*L2E)
      wo[m] = -L2E * w_hh[(12 + j) * 4 + jm];
    }
    float ct = 0.0f, h0 = 0.0f, h1v = 0.0f, h2v = 0.0f, h3v = 0.0f;

    __syncthreads();  // wait for proj to fill xaBuf[0]

    for (int p = 0; p < PH; ++p) {
      const int d = p & 1;
      float4 xa[SPH];
      #pragma unroll
      for (int k = 0; k < SPH; ++k) xa[k] = xaBuf[d][rw][k][lane];  // ds_read_b128

      #pragma unroll
      for (int k = 0; k < SPH; ++k) {
        // four gate pre-activations (balanced trees, 4 independent chains)
        float ti = fmaf(wi[1], h1v, fmaf(wi[0], h0, xa[k].x));
        ti += fmaf(wi[3], h3v, wi[2] * h2v);
        float tf = fmaf(wf[1], h1v, fmaf(wf[0], h0, xa[k].y));
        tf += fmaf(wf[3], h3v, wf[2] * h2v);
        float tg = fmaf(wg[1], h1v, fmaf(wg[0], h0, xa[k].z));
        tg += fmaf(wg[3], h3v, wg[2] * h2v);
        float to = fmaf(wo[1], h1v, fmaf(wo[0], h0, xa[k].w));
        to += fmaf(wo[3], h3v, wo[2] * h2v);

        const float Ei = __builtin_amdgcn_exp2f(ti);
        const float Ef = __builtin_amdgcn_exp2f(tf);
        const float Eg = __builtin_amdgcn_exp2f(tg);
        const float Eo = __builtin_amdgcn_exp2f(to);
        const float di  = 1.0f + Ei, df_ = 1.0f + Ef;
        const float dg  = 1.0f + Eg, do_ = 1.0f + Eo;
        const float r1 = __builtin_amdgcn_rcpf(di * df_);   // shared rcp (i,f)
        const float r2 = __builtin_amdgcn_rcpf(dg * do_);   // shared rcp (g,o)
        const float gi = r1 * df_;                  // sigma(i)
        const float gf = r1 * di;                   // sigma(f)
        const float yG = r2 * do_;                  // sigma(2g)
        const float go = r2 * dg;                   // sigma(o)
        const float tgp = fmaf(2.0f * cm2, yG, -cm2);  // cm2*tanh(g)
        const float P = gi * tgp;
        ct = fmaf(gf, ct, P);                       // ct = cm2 * c
        const float zc = __builtin_amdgcn_exp2f(ct);
        const float rc = __builtin_amdgcn_rcpf(1.0f + zc);
        const float o2 = go + go;
        const float hn = fmaf(o2, rc, -go);         // o * tanh(c)
        h0  = hn;                                   // h of unit j
        h1v = dpp_qxor1(hn);                        // h of unit j^1
        h2v = dpp_qxor2(hn);
        h3v = dpp_qxor3(hn);
        hnBuf[d][rw][lane][k] = hn;
      }
      __syncthreads();
    }
  } else if (wid < 4) {
    // ---------------- proj/load waves ----------------
    const int b = blockIdx.x * 32 + rw * 16 + g;
    float wii[4], wif[4], wig[4], wio[4];
    #pragma unroll
    for (int m = 0; m < 4; ++m) {
      const int jm = j ^ m;
      wii[m] = -L2E * w_ih[(0  + j) * 4 + jm];
      wif[m] = -L2E * w_ih[(4  + j) * 4 + jm];
      wig[m] = cm2  * w_ih[(8  + j) * 4 + jm];
      wio[m] = -L2E * w_ih[(12 + j) * 4 + jm];
    }
    const float bi = -L2E * (b_ih[j]      + b_hh[j]);
    const float bf = -L2E * (b_ih[4 + j]  + b_hh[4 + j]);
    const float bg = cm2  * (b_ih[8 + j]  + b_hh[8 + j]);
    const float bo = -L2E * (b_ih[12 + j] + b_hh[12 + j]);

    const int XS = B_DIM * 4;
    const int xoff = b * 4 + j;

    float xc[SPH], xn[SPH];

    auto load8 = [&](float (&dst)[SPH], int ph) {
      const int base = xoff + ((ph & (PH - 1)) * SPH) * XS;  // wrap: harmless
      #pragma unroll
      for (int k = 0; k < SPH; ++k) dst[k] = x[base + k * XS];
    };
    auto projWrite = [&](const float (&xr)[SPH], int dd) {
      #pragma unroll
      for (int k = 0; k < SPH; ++k) {
        const float xe = xr[k];                 // x[b][j]
        const float x1 = dpp_qxor1(xe);         // x[b][j^1]
        const float x2 = dpp_qxor2(xe);
        const float x3 = dpp_qxor3(xe);
        float ui = fmaf(wii[0], xe, bi);
        ui = fmaf(wii[1], x1, ui); ui = fmaf(wii[2], x2, ui); ui = fmaf(wii[3], x3, ui);
        float uf = fmaf(wif[0], xe, bf);
        uf = fmaf(wif[1], x1, uf); uf = fmaf(wif[2], x2, uf); uf = fmaf(wif[3], x3, uf);
        float ug = fmaf(wig[0], xe, bg);
        ug = fmaf(wig[1], x1, ug); ug = fmaf(wig[2], x2, ug); ug = fmaf(wig[3], x3, ug);
        float uo = fmaf(wio[0], xe, bo);
        uo = fmaf(wio[1], x1, uo); uo = fmaf(wio[2], x2, uo); uo = fmaf(wio[3], x3, uo);
        xaBuf[dd][rw][k][lane] = make_float4(ui, uf, ug, uo);  // ds_write_b128
      }
    };

    // prologue: xa for phase 0 -> buf0; start loading x for phase 1
    load8(xc, 0);
    projWrite(xc, 0);
    load8(xn, 1);
    __syncthreads();

    for (int pp = 0; pp < PH; pp += 2) {
      projWrite(xn, 1);           // xa(pp+1) -> buf1
      load8(xc, pp + 2);
      __syncthreads();
      projWrite(xc, 0);           // xa(pp+2) -> buf0
      load8(xn, pp + 3);
      __syncthreads();
    }
  } else {
    // ---------------- head/store waves ----------------
    const int ge = lane & 15;        // element
    const int su = lane >> 4;        // step sub-index (0..3); handles su, su+4
    const int ob = blockIdx.x * 32 + rw * 16 + ge;
    float wl[4];
    #pragma unroll
    for (int m = 0; m < 4; ++m) wl[m] = -L2E * w_lin[m];
    const float blin = -L2E * b_lin[0];

    __syncthreads();  // initial barrier (matches other roles)

    for (int p = 0; p < PH; ++p) {
      __syncthreads();  // barrier ending phase p -> hnBuf[p&1] complete
      const int dh = p & 1;
      #pragma unroll
      for (int s2 = 0; s2 < 2; ++s2) {
        const int s = su + s2 * 4;
        const float v0 = hnBuf[dh][rw][4 * ge + 0][s];
        const float v1 = hnBuf[dh][rw][4 * ge + 1][s];
        const float v2 = hnBuf[dh][rw][4 * ge + 2][s];
        const float v3 = hnBuf[dh][rw][4 * ge + 3][s];
        float mm = fmaf(wl[0], v0, blin);
        mm = fmaf(wl[1], v1, mm);
        mm = fmaf(wl[2], v2, mm);
        mm = fmaf(wl[3], v3, mm);
        const float o = __builtin_amdgcn_rcpf(1.0f + __builtin_amdgcn_exp2f(mm));
        out[(size_t)(p * SPH + s) * B_DIM + ob] = o;
      }
    }
  }
}

extern "C" void kernel_launch(void* const* d_in, const int* in_sizes, int n_in,
                              void* d_out, int out_size, void* d_ws, size_t ws_size,
                              hipStream_t stream) {
  const float* x     = (const float*)d_in[0];
  const float* w_ih  = (const float*)d_in[1];
  const float* w_hh  = (const float*)d_in[2];
  const float* b_ih  = (const float*)d_in[3];
  const float* b_hh  = (const float*)d_in[4];
  const float* w_lin = (const float*)d_in[5];
  const float* b_lin = (const float*)d_in[6];
  float* out = (float*)d_out;

  // 256 blocks x 384 threads (2 rec + 2 proj + 2 head waves), 32 elems/block,
  // 1 block/CU. wid%4 placement: SIMD0/1 <- {rec, head}, SIMD2/3 <- {proj}.
  // lambda=4: all four gates in-lane -> no mirror exchange, 16 elems/rec wave.
  dim3 block(384);
  dim3 grid(B_DIM / 32);
  hipLaunchKernelGGL(lstm_l4_kernel, grid, block, 0, stream,
                     x, w_ih, w_hh, b_ih, b_hh, w_lin, b_lin, out);
}

// Round 16
// 233.225 us; speedup vs baseline: 1.0268x; 1.0147x over previous
//
#include <hip/hip_runtime.h>

#define T_DIM 2048
#define B_DIM 8192
#define PH    256   // phases
#define SPH   8     // steps per phase

// DPP cross-lane helpers (pure VALU)
__device__ __forceinline__ float dpp_qxor1(float v) {
  int i = __float_as_int(v);
  return __int_as_float(__builtin_amdgcn_update_dpp(i, i, 0xB1, 0xF, 0xF, false)); // [1,0,3,2]
}
__device__ __forceinline__ float dpp_qxor2(float v) {
  int i = __float_as_int(v);
  return __int_as_float(__builtin_amdgcn_update_dpp(i, i, 0x4E, 0xF, 0xF, false)); // [2,3,0,1]
}
__device__ __forceinline__ float dpp_qxor3(float v) {
  int i = __float_as_int(v);
  return __int_as_float(__builtin_amdgcn_update_dpp(i, i, 0x1B, 0xF, 0xF, false)); // [3,2,1,0]
}

__global__ __launch_bounds__(256) void lstm_r16_kernel(
    const float* __restrict__ x,
    const float* __restrict__ w_ih, const float* __restrict__ w_hh,
    const float* __restrict__ b_ih, const float* __restrict__ b_hh,
    const float* __restrict__ w_lin, const float* __restrict__ b_lin,
    float* __restrict__ out)
{
  // xa: per lane (elem g, unit j) the four gate pre-activations (i,f,g,o)
  __shared__ float4 xaBuf[2][2][SPH][64];   // [slot][rw][k][lane]
  __shared__ float  hnBuf[2][2][64][9];     // [slot][rw][lane(4g+j)][k]

  const int tid  = threadIdx.x;
  const int wid  = tid >> 6;       // 0,1: rec -> SIMD0,1 (solo); 2,3: proj+head -> SIMD2,3
  const int lane = tid & 63;
  const int rw   = wid & 1;        // wave index within role

  const float L2E = 1.4426950408889634f;
  const float cm2 = -2.0f * L2E;

  const int g = lane >> 2;         // element within wave (0..15)
  const int j = lane & 3;          // hidden unit owned by this lane

  if (wid < 2) {
    // ---------------- recurrence waves (solo on SIMD0/1): 257 barriers ----------------
    __builtin_amdgcn_s_setprio(1);
    float wi[4], wf[4], wg[4], wo[4];   // permuted: index m pairs with h_{j^m}
    #pragma unroll
    for (int m = 0; m < 4; ++m) {
      const int jm = j ^ m;
      wi[m] = -L2E * w_hh[(0  + j) * 4 + jm];
      wf[m] = -L2E * w_hh[(4  + j) * 4 + jm];
      wg[m] = cm2  * w_hh[(8  + j) * 4 + jm];   // tanh pre-scale (-2*L2E)
      wo[m] = -L2E * w_hh[(12 + j) * 4 + jm];
    }
    float ct = 0.0f, h0 = 0.0f, h1v = 0.0f, h2v = 0.0f, h3v = 0.0f;

    __syncthreads();  // wait for proj to fill xaBuf[0]

    for (int p = 0; p < PH; ++p) {
      const int d = p & 1;
      float4 xa[SPH];
      #pragma unroll
      for (int k = 0; k < SPH; ++k) xa[k] = xaBuf[d][rw][k][lane];  // ds_read_b128

      #pragma unroll
      for (int k = 0; k < SPH; ++k) {
        // four gate pre-activations (balanced trees, 4 independent chains)
        float ti = fmaf(wi[1], h1v, fmaf(wi[0], h0, xa[k].x));
        ti += fmaf(wi[3], h3v, wi[2] * h2v);
        float tf = fmaf(wf[1], h1v, fmaf(wf[0], h0, xa[k].y));
        tf += fmaf(wf[3], h3v, wf[2] * h2v);
        float tg = fmaf(wg[1], h1v, fmaf(wg[0], h0, xa[k].z));
        tg += fmaf(wg[3], h3v, wg[2] * h2v);
        float to = fmaf(wo[1], h1v, fmaf(wo[0], h0, xa[k].w));
        to += fmaf(wo[3], h3v, wo[2] * h2v);

        const float Ei = __builtin_amdgcn_exp2f(ti);
        const float Ef = __builtin_amdgcn_exp2f(tf);
        const float Eg = __builtin_amdgcn_exp2f(tg);
        const float Eo = __builtin_amdgcn_exp2f(to);
        const float di  = 1.0f + Ei, df_ = 1.0f + Ef;
        const float dg  = 1.0f + Eg, do_ = 1.0f + Eo;
        const float r1 = __builtin_amdgcn_rcpf(di * df_);   // shared rcp (i,f)
        const float r2 = __builtin_amdgcn_rcpf(dg * do_);   // shared rcp (g,o)
        const float gi = r1 * df_;                  // sigma(i)
        const float gf = r1 * di;                   // sigma(f)
        const float yG = r2 * do_;                  // sigma(2g)
        const float go = r2 * dg;                   // sigma(o)
        const float tgp = fmaf(2.0f * cm2, yG, -cm2);  // cm2*tanh(g)
        const float P = gi * tgp;
        ct = fmaf(gf, ct, P);                       // ct = cm2 * c
        const float zc = __builtin_amdgcn_exp2f(ct);
        const float rc = __builtin_amdgcn_rcpf(1.0f + zc);
        const float o2 = go + go;
        const float hn = fmaf(o2, rc, -go);         // o * tanh(c)
        h0  = hn;                                   // h of unit j
        h1v = dpp_qxor1(hn);                        // h of unit j^1
        h2v = dpp_qxor2(hn);
        h3v = dpp_qxor3(hn);
        hnBuf[d][rw][lane][k] = hn;
      }
      __syncthreads();
    }
  } else {
    // ---------------- proj+head waves (SIMD2/3): 257 barriers ----------------
    const int b = blockIdx.x * 32 + rw * 16 + g;
    float wii[4], wif[4], wig[4], wio[4];
    #pragma unroll
    for (int m = 0; m < 4; ++m) {
      const int jm = j ^ m;
      wii[m] = -L2E * w_ih[(0  + j) * 4 + jm];
      wif[m] = -L2E * w_ih[(4  + j) * 4 + jm];
      wig[m] = cm2  * w_ih[(8  + j) * 4 + jm];
      wio[m] = -L2E * w_ih[(12 + j) * 4 + jm];
    }
    const float bi = -L2E * (b_ih[j]      + b_hh[j]);
    const float bf = -L2E * (b_ih[4 + j]  + b_hh[4 + j]);
    const float bg = cm2  * (b_ih[8 + j]  + b_hh[8 + j]);
    const float bo = -L2E * (b_ih[12 + j] + b_hh[12 + j]);

    // head assignment: lane -> (elem ge, step sub-index su); 2 outputs/lane/phase
    const int ge = lane & 15;
    const int su = lane >> 4;        // handles steps su, su+4
    const int ob = blockIdx.x * 32 + rw * 16 + ge;
    float wl[4];
    #pragma unroll
    for (int m = 0; m < 4; ++m) wl[m] = -L2E * w_lin[m];
    const float blin = -L2E * b_lin[0];

    const int XS = B_DIM * 4;
    const int xoff = b * 4 + j;

    float xc[SPH], xn[SPH];

    auto load8 = [&](float (&dst)[SPH], int ph) {
      const int base = xoff + ((ph & (PH - 1)) * SPH) * XS;  // wrap: harmless
      #pragma unroll
      for (int k = 0; k < SPH; ++k) dst[k] = x[base + k * XS];
    };
    auto projWrite = [&](const float (&xr)[SPH], int dd) {
      #pragma unroll
      for (int k = 0; k < SPH; ++k) {
        const float xe = xr[k];                 // x[b][j]
        const float x1 = dpp_qxor1(xe);         // x[b][j^1]
        const float x2 = dpp_qxor2(xe);
        const float x3 = dpp_qxor3(xe);
        float ui = fmaf(wii[0], xe, bi);
        ui = fmaf(wii[1], x1, ui); ui = fmaf(wii[2], x2, ui); ui = fmaf(wii[3], x3, ui);
        float uf = fmaf(wif[0], xe, bf);
        uf = fmaf(wif[1], x1, uf); uf = fmaf(wif[2], x2, uf); uf = fmaf(wif[3], x3, uf);
        float ug = fmaf(wig[0], xe, bg);
        ug = fmaf(wig[1], x1, ug); ug = fmaf(wig[2], x2, ug); ug = fmaf(wig[3], x3, ug);
        float uo = fmaf(wio[0], xe, bo);
        uo = fmaf(wio[1], x1, uo); uo = fmaf(wio[2], x2, uo); uo = fmaf(wio[3], x3, uo);
        xaBuf[dd][rw][k][lane] = make_float4(ui, uf, ug, uo);  // ds_write_b128
      }
    };
    auto headStore = [&](int p) {
      const int dh = p & 1;
      #pragma unroll
      for (int s2 = 0; s2 < 2; ++s2) {
        const int s = su + s2 * 4;
        const float v0 = hnBuf[dh][rw][4 * ge + 0][s];
        const float v1 = hnBuf[dh][rw][4 * ge + 1][s];
        const float v2 = hnBuf[dh][rw][4 * ge + 2][s];
        const float v3 = hnBuf[dh][rw][4 * ge + 3][s];
        float mm = fmaf(wl[0], v0, blin);
        mm = fmaf(wl[1], v1, mm);
        mm = fmaf(wl[2], v2, mm);
        mm = fmaf(wl[3], v3, mm);
        const float o = __builtin_amdgcn_rcpf(1.0f + __builtin_amdgcn_exp2f(mm));
        out[(size_t)(p * SPH + s) * B_DIM + ob] = o;
      }
    };

    // prologue: xa for phase 0 -> buf0; start loading x for phase 1
    load8(xc, 0);
    projWrite(xc, 0);
    load8(xn, 1);
    __syncthreads();

    for (int pp = 0; pp < PH; pp += 2) {
      // phase pp: write xa(pp+1)->buf1; load x(pp+2); head(pp-1)
      projWrite(xn, 1);
      load8(xc, pp + 2);
      if (pp > 0) headStore(pp - 1);
      __syncthreads();
      // phase pp+1: write xa(pp+2)->buf0; load x(pp+3); head(pp)
      projWrite(xc, 0);
      load8(xn, pp + 3);
      headStore(pp);
      __syncthreads();
    }
    headStore(PH - 1);  // final phase's head (rec may have exited; slot stable)
  }
}

extern "C" void kernel_launch(void* const* d_in, const int* in_sizes, int n_in,
                              void* d_out, int out_size, void* d_ws, size_t ws_size,
                              hipStream_t stream) {
  const float* x     = (const float*)d_in[0];
  const float* w_ih  = (const float*)d_in[1];
  const float* w_hh  = (const float*)d_in[2];
  const float* b_ih  = (const float*)d_in[3];
  const float* b_hh  = (const float*)d_in[4];
  const float* w_lin = (const float*)d_in[5];
  const float* b_lin = (const float*)d_in[6];
  float* out = (float*)d_out;

  // 256 blocks x 256 threads (2 rec + 2 proj+head waves), 32 elems/block,
  // 1 block/CU. wid%4 placement: rec waves SOLO on SIMD0/1; proj (with head
  // merged in) on SIMD2/3. lambda=4 rec: no mirror exchange, 16 elems/wave.
  dim3 block(256);
  dim3 grid(B_DIM / 32);
  hipLaunchKernelGGL(lstm_r16_kernel, grid, block, 0, stream,
                     x, w_ih, w_hh, b_ih, b_hh, w_lin, b_lin, out);
}